// Round 6
// baseline (113.759 us; speedup 1.0000x reference)
//
#include <hip/hip_runtime.h>
#include <stdint.h>

// VectorQuantizer: x[32,64,64,64] NCHW fp32, W[512,64] fp32.
// argmin_k ||x - w_k||^2 ; out = W[argmin] in NCHW.
//
// v6: 512-thr blocks (8 waves x 32 tokens), 32x32x16 bf16 MFMA, full codebook
// in LDS in dim-octet-major layout (conflict-free immediate-offset ds_reads),
// 2-pass (max, rescan-mask) margin-certified argmax, fp64 refine for
// multi-candidate tokens. launch_bounds(512,4): 128 VGPR, 16 waves/CU.

typedef short short8 __attribute__((ext_vector_type(8)));
typedef float f32x4 __attribute__((ext_vector_type(4)));
typedef float f32x16 __attribute__((ext_vector_type(16)));

#define HW_ 4096

__device__ __forceinline__ unsigned short f2bf(float f) {
    unsigned u = __float_as_uint(f);
    u += 0x7fff + ((u >> 16) & 1);   // RNE to bf16
    return (unsigned short)(u >> 16);
}

// Image: ushort idx(k,d) = (d>>3)*4096 + k*8 + (d&7)   [8 subblocks of 8KiB]
__global__ __launch_bounds__(64) void vq_prep(const float* __restrict__ W,
                                              unsigned short* __restrict__ Wb,
                                              float* __restrict__ nh,
                                              int* __restrict__ wmax2i) {
    const int k = blockIdx.x, l = threadIdx.x;
    float v = W[k * 64 + l];
    Wb[(l >> 3) * 4096 + k * 8 + (l & 7)] = f2bf(v);
    float s = v * v;
    #pragma unroll
    for (int off = 1; off < 64; off <<= 1) s += __shfl_xor(s, off);
    if (l == 0) {
        nh[k] = -0.5f * s;
        atomicMax(wmax2i, __float_as_int(s));   // s > 0: int order == float order
    }
}

__global__ __launch_bounds__(512, 4) void vq_main(const float* __restrict__ x,
                                                  const float* __restrict__ W,
                                                  const unsigned short* __restrict__ Wb,
                                                  const float* __restrict__ nh,
                                                  const int* __restrict__ wmax2i,
                                                  float* __restrict__ out) {
    __shared__ unsigned short cb[32768];   // 64 KiB codebook, dim-octet-major
    __shared__ float nhs[512];             // -0.5*||w||^2
    __shared__ int bkArr[256];

    const int tid = threadIdx.x;
    const int bid = blockIdx.x;
    const int b = bid >> 4;                 // batch
    const int p0 = (bid & 15) << 8;         // 256-token spatial base
    const int l = tid & 63;
    const int wv = tid >> 6;                // wave 0..7
    const int col = l & 31;                 // token col in MFMA
    const int hi = l >> 5;                  // half-wave
    const int tokb = wv * 32 + col;         // token in block 0..255

    // ---- stage codebook + nhs (linear, conflict-free) ----
    {
        const f32x4* src = (const f32x4*)Wb;
        f32x4* dst = (f32x4*)cb;
        #pragma unroll
        for (int i = 0; i < 8; ++i) dst[tid + i * 512] = src[tid + i * 512];
        nhs[tid] = nh[tid];
    }

    // ---- B fragments direct from global; xsq on the fly ----
    short8 bf[4];
    float xsq = 0.f;
    const float* xb = x + (size_t)b * 262144 + p0 + tokb;
    #pragma unroll
    for (int s = 0; s < 4; ++s) {
        #pragma unroll
        for (int e = 0; e < 8; ++e) {
            float v = xb[(size_t)(s * 16 + hi * 8 + e) * HW_];
            xsq += v * v;
            bf[s][e] = (short)f2bf(v);
        }
    }
    xsq += __shfl_xor(xsq, 32);
    const float wm2 = __int_as_float(*wmax2i);
    const float margin = ldexpf(sqrtf(xsq * wm2), -8) + 0.01f;
    __syncthreads();

    const char* Ab = (const char*)cb + hi * 8192 + col * 16;

    // score tile T: codes T*32 + row(reg,hi), row = (reg&3)+8*(reg>>2)+4*hi
    #define KT(T, AU) do {                                                         \
        AU.q[0] = *(const f32x4*)(&nhs[(T) * 32 + hi * 4]);                        \
        AU.q[1] = *(const f32x4*)(&nhs[(T) * 32 + 8 + hi * 4]);                    \
        AU.q[2] = *(const f32x4*)(&nhs[(T) * 32 + 16 + hi * 4]);                   \
        AU.q[3] = *(const f32x4*)(&nhs[(T) * 32 + 24 + hi * 4]);                   \
        short8 a0 = *(const short8*)(Ab + (T) * 512);                              \
        short8 a1 = *(const short8*)(Ab + 16384 + (T) * 512);                      \
        short8 a2 = *(const short8*)(Ab + 32768 + (T) * 512);                      \
        short8 a3 = *(const short8*)(Ab + 49152 + (T) * 512);                      \
        AU.v = __builtin_amdgcn_mfma_f32_32x32x16_bf16(a0, bf[0], AU.v, 0, 0, 0);  \
        AU.v = __builtin_amdgcn_mfma_f32_32x32x16_bf16(a1, bf[1], AU.v, 0, 0, 0);  \
        AU.v = __builtin_amdgcn_mfma_f32_32x32x16_bf16(a2, bf[2], AU.v, 0, 0, 0);  \
        AU.v = __builtin_amdgcn_mfma_f32_32x32x16_bf16(a3, bf[3], AU.v, 0, 0, 0);  \
    } while (0)

    // ---- pass 1: running max ----
    float m = -3.4e38f;
    #pragma unroll
    for (int T = 0; T < 16; ++T) {
        union { f32x16 v; f32x4 q[4]; } au;
        KT(T, au);
        #pragma unroll
        for (int r = 0; r < 16; ++r) m = fmaxf(m, au.v[r]);
    }
    m = fmaxf(m, __shfl_xor(m, 32));
    const float thr = m - margin;

    // ---- pass 2: rescan, build 256-bit candidate mask (bit = T*16 + reg) ----
    uint64_t msk[4] = {0, 0, 0, 0};
    #pragma unroll
    for (int T = 0; T < 16; ++T) {
        union { f32x16 v; f32x4 q[4]; } au;
        KT(T, au);
        unsigned mt = 0;
        #pragma unroll
        for (int r = 0; r < 16; ++r) mt |= (au.v[r] >= thr ? 1u : 0u) << r;
        msk[T >> 2] |= (uint64_t)mt << ((T & 3) * 16);
    }
    #undef KT

    const int cnt = __popcll(msk[0]) + __popcll(msk[1]) + __popcll(msk[2]) + __popcll(msk[3]);
    const int cntT = cnt + __shfl_xor(cnt, 32);

    // singleton fast path
    int klocal = 0x7fffffff;
    if (cnt == 1) {
        int idx = 0;
        #pragma unroll
        for (int w = 0; w < 4; ++w)
            if (msk[w]) idx = w * 64 + __builtin_ctzll(msk[w]);
        int reg = idx & 15, T = idx >> 4;
        klocal = T * 32 + (reg & 3) + 8 * (reg >> 2) + 4 * hi;
    }
    int kmin = min(klocal, __shfl_xor(klocal, 32));

    // multi-candidate: exact fp64 sum((x-w)^2), wave-cooperative
    double bd = 1.0e308;
    int bkm = 0x7fffffff;
    const bool multi = (cntT > 1);
    if (!multi) { msk[0] = msk[1] = msk[2] = msk[3] = 0; }
    uint64_t wmask = __ballot((msk[0] | msk[1] | msk[2] | msk[3]) != 0ull);
    while (wmask) {
        int L = __builtin_ctzll(wmask);
        wmask &= wmask - 1;
        const int hiL = L >> 5;
        const int tokL = wv * 32 + (L & 31);
        double xvd = (double)x[(size_t)b * 262144 + (size_t)l * HW_ + p0 + tokL];
        #pragma unroll
        for (int w = 0; w < 4; ++w) {
            uint64_t mm = __shfl(msk[w], L);
            while (mm) {
                int bit = __builtin_ctzll(mm); mm &= mm - 1;
                int idx = w * 64 + bit;
                int reg = idx & 15, T = idx >> 4;
                int k = T * 32 + (reg & 3) + 8 * (reg >> 2) + 4 * hiL;
                double dl = xvd - (double)W[k * 64 + l];
                double p = dl * dl;
                #pragma unroll
                for (int off = 1; off < 64; off <<= 1) p += __shfl_xor(p, off);
                if (l == L && (p < bd || (p == bd && k < bkm))) { bd = p; bkm = k; }
            }
        }
    }
    {   // lexicographic merge across the token's two lanes
        double od = __shfl_xor(bd, 32); int ok = __shfl_xor(bkm, 32);
        if (od < bd || (od == bd && ok < bkm)) { bd = od; bkm = ok; }
    }
    const int bk = multi ? bkm : kmin;

    if (hi == 0) bkArr[tokb] = bk;
    __syncthreads();

    // ---- epilogue: gather W rows (L2-hot), coalesced NCHW store ----
    {
        const int pp = tid & 255;            // token
        const int dh = tid >> 8;             // dim half 0..1
        const int kk = bkArr[pp];
        const float* wr = W + kk * 64 + dh * 32;
        float* ob = out + (size_t)b * 262144 + p0 + pp;
        #pragma unroll
        for (int j = 0; j < 8; ++j) {
            f32x4 v = *(const f32x4*)(wr + j * 4);
            ob[(size_t)(dh * 32 + j * 4 + 0) * HW_] = v[0];
            ob[(size_t)(dh * 32 + j * 4 + 1) * HW_] = v[1];
            ob[(size_t)(dh * 32 + j * 4 + 2) * HW_] = v[2];
            ob[(size_t)(dh * 32 + j * 4 + 3) * HW_] = v[3];
        }
    }
}

extern "C" void kernel_launch(void* const* d_in, const int* in_sizes, int n_in,
                              void* d_out, int out_size, void* d_ws, size_t ws_size,
                              hipStream_t stream) {
    const float* x = (const float*)d_in[0];
    const float* W = (const float*)d_in[1];
    unsigned short* Wb = (unsigned short*)d_ws;              // 64 KiB image
    float* nh = (float*)((char*)d_ws + 65536);               // 512 f32
    int* wmax2i = (int*)((char*)d_ws + 65536 + 2048);        // 1 int (float bits)
    hipMemsetAsync(wmax2i, 0, 4, stream);
    vq_prep<<<512, 64, 0, stream>>>(W, Wb, nh, wmax2i);
    vq_main<<<512, 512, 0, stream>>>(x, W, Wb, nh, wmax2i, (float*)d_out);
}

// Round 7
// 93.449 us; speedup vs baseline: 1.2173x; 1.2173x over previous
//
#include <hip/hip_runtime.h>
#include <stdint.h>

// VectorQuantizer: x[32,64,64,64] NCHW fp32, W[512,64] fp32.
// argmin_k ||x - w_k||^2 ; out = W[argmin] in NCHW.
//
// v7 = v6 with the register cap fixed (launch_bounds(512,2): <=256 unified regs,
// no spill) and the certified margin at its sound value 2^-7*||x||*Wmax + 0.02.
// Structure: 512-thr blocks (8 waves x 32 tokens), 32x32x16 bf16 MFMA, full
// codebook in LDS dim-octet-major (conflict-free immediate-offset ds_reads),
// 2-pass (max, rescan-mask) margin-certified argmax, fp64 refine for
// multi-candidate tokens, coalesced direct-global I/O.

typedef short short8 __attribute__((ext_vector_type(8)));
typedef float f32x4 __attribute__((ext_vector_type(4)));
typedef float f32x16 __attribute__((ext_vector_type(16)));

#define HW_ 4096

__device__ __forceinline__ unsigned short f2bf(float f) {
    unsigned u = __float_as_uint(f);
    u += 0x7fff + ((u >> 16) & 1);   // RNE to bf16
    return (unsigned short)(u >> 16);
}

// Image: ushort idx(k,d) = (d>>3)*4096 + k*8 + (d&7)   [8 subblocks of 8KiB]
__global__ __launch_bounds__(64) void vq_prep(const float* __restrict__ W,
                                              unsigned short* __restrict__ Wb,
                                              float* __restrict__ nh,
                                              int* __restrict__ wmax2i) {
    const int k = blockIdx.x, l = threadIdx.x;
    float v = W[k * 64 + l];
    Wb[(l >> 3) * 4096 + k * 8 + (l & 7)] = f2bf(v);
    float s = v * v;
    #pragma unroll
    for (int off = 1; off < 64; off <<= 1) s += __shfl_xor(s, off);
    if (l == 0) {
        nh[k] = -0.5f * s;
        atomicMax(wmax2i, __float_as_int(s));   // s > 0: int order == float order
    }
}

__global__ __launch_bounds__(512, 2) void vq_main(const float* __restrict__ x,
                                                  const float* __restrict__ W,
                                                  const unsigned short* __restrict__ Wb,
                                                  const float* __restrict__ nh,
                                                  const int* __restrict__ wmax2i,
                                                  float* __restrict__ out) {
    __shared__ unsigned short cb[32768];   // 64 KiB codebook, dim-octet-major
    __shared__ float nhs[512];             // -0.5*||w||^2
    __shared__ int bkArr[256];

    const int tid = threadIdx.x;
    const int bid = blockIdx.x;
    const int b = bid >> 4;                 // batch
    const int p0 = (bid & 15) << 8;         // 256-token spatial base
    const int l = tid & 63;
    const int wv = tid >> 6;                // wave 0..7
    const int col = l & 31;                 // token col in MFMA
    const int hi = l >> 5;                  // half-wave
    const int tokb = wv * 32 + col;         // token in block 0..255

    // ---- stage codebook + nhs (linear, conflict-free) ----
    {
        const f32x4* src = (const f32x4*)Wb;
        f32x4* dst = (f32x4*)cb;
        #pragma unroll
        for (int i = 0; i < 8; ++i) dst[tid + i * 512] = src[tid + i * 512];
        nhs[tid] = nh[tid];
    }

    // ---- B fragments direct from global; xsq on the fly ----
    short8 bf[4];
    float xsq = 0.f;
    const float* xb = x + (size_t)b * 262144 + p0 + tokb;
    #pragma unroll
    for (int s = 0; s < 4; ++s) {
        #pragma unroll
        for (int e = 0; e < 8; ++e) {
            float v = xb[(size_t)(s * 16 + hi * 8 + e) * HW_];
            xsq += v * v;
            bf[s][e] = (short)f2bf(v);
        }
    }
    xsq += __shfl_xor(xsq, 32);
    const float wm2 = __int_as_float(*wmax2i);
    const float margin = ldexpf(sqrtf(xsq * wm2), -7) + 0.02f;  // 2E certified
    __syncthreads();

    const char* Ab = (const char*)cb + hi * 8192 + col * 16;

    // score tile T: codes T*32 + row(reg,hi), row = (reg&3)+8*(reg>>2)+4*hi
    #define KT(T, AU) do {                                                         \
        AU.q[0] = *(const f32x4*)(&nhs[(T) * 32 + hi * 4]);                        \
        AU.q[1] = *(const f32x4*)(&nhs[(T) * 32 + 8 + hi * 4]);                    \
        AU.q[2] = *(const f32x4*)(&nhs[(T) * 32 + 16 + hi * 4]);                   \
        AU.q[3] = *(const f32x4*)(&nhs[(T) * 32 + 24 + hi * 4]);                   \
        short8 a0 = *(const short8*)(Ab + (T) * 512);                              \
        short8 a1 = *(const short8*)(Ab + 16384 + (T) * 512);                      \
        short8 a2 = *(const short8*)(Ab + 32768 + (T) * 512);                      \
        short8 a3 = *(const short8*)(Ab + 49152 + (T) * 512);                      \
        AU.v = __builtin_amdgcn_mfma_f32_32x32x16_bf16(a0, bf[0], AU.v, 0, 0, 0);  \
        AU.v = __builtin_amdgcn_mfma_f32_32x32x16_bf16(a1, bf[1], AU.v, 0, 0, 0);  \
        AU.v = __builtin_amdgcn_mfma_f32_32x32x16_bf16(a2, bf[2], AU.v, 0, 0, 0);  \
        AU.v = __builtin_amdgcn_mfma_f32_32x32x16_bf16(a3, bf[3], AU.v, 0, 0, 0);  \
    } while (0)

    // ---- pass 1: running max ----
    float m = -3.4e38f;
    #pragma unroll
    for (int T = 0; T < 16; ++T) {
        union { f32x16 v; f32x4 q[4]; } au;
        KT(T, au);
        #pragma unroll
        for (int r = 0; r < 16; ++r) m = fmaxf(m, au.v[r]);
    }
    m = fmaxf(m, __shfl_xor(m, 32));
    const float thr = m - margin;

    // ---- pass 2: rescan, build 256-bit candidate mask (bit = T*16 + reg) ----
    uint64_t msk[4] = {0, 0, 0, 0};
    #pragma unroll
    for (int T = 0; T < 16; ++T) {
        union { f32x16 v; f32x4 q[4]; } au;
        KT(T, au);
        unsigned mt = 0;
        #pragma unroll
        for (int r = 0; r < 16; ++r) mt |= (au.v[r] >= thr ? 1u : 0u) << r;
        msk[T >> 2] |= (uint64_t)mt << ((T & 3) * 16);
    }
    #undef KT

    const int cnt = __popcll(msk[0]) + __popcll(msk[1]) + __popcll(msk[2]) + __popcll(msk[3]);
    const int cntT = cnt + __shfl_xor(cnt, 32);

    // singleton fast path
    int klocal = 0x7fffffff;
    if (cnt == 1) {
        int idx = 0;
        #pragma unroll
        for (int w = 0; w < 4; ++w)
            if (msk[w]) idx = w * 64 + __builtin_ctzll(msk[w]);
        int reg = idx & 15, T = idx >> 4;
        klocal = T * 32 + (reg & 3) + 8 * (reg >> 2) + 4 * hi;
    }
    int kmin = min(klocal, __shfl_xor(klocal, 32));

    // multi-candidate: exact fp64 sum((x-w)^2), wave-cooperative
    double bd = 1.0e308;
    int bkm = 0x7fffffff;
    const bool multi = (cntT > 1);
    if (!multi) { msk[0] = msk[1] = msk[2] = msk[3] = 0; }
    uint64_t wmask = __ballot((msk[0] | msk[1] | msk[2] | msk[3]) != 0ull);
    while (wmask) {
        int L = __builtin_ctzll(wmask);
        wmask &= wmask - 1;
        const int hiL = L >> 5;
        const int tokL = wv * 32 + (L & 31);
        double xvd = (double)x[(size_t)b * 262144 + (size_t)l * HW_ + p0 + tokL];
        #pragma unroll
        for (int w = 0; w < 4; ++w) {
            uint64_t mm = __shfl(msk[w], L);
            while (mm) {
                int bit = __builtin_ctzll(mm); mm &= mm - 1;
                int idx = w * 64 + bit;
                int reg = idx & 15, T = idx >> 4;
                int k = T * 32 + (reg & 3) + 8 * (reg >> 2) + 4 * hiL;
                double dl = xvd - (double)W[k * 64 + l];
                double p = dl * dl;
                #pragma unroll
                for (int off = 1; off < 64; off <<= 1) p += __shfl_xor(p, off);
                if (l == L && (p < bd || (p == bd && k < bkm))) { bd = p; bkm = k; }
            }
        }
    }
    {   // lexicographic merge across the token's two lanes
        double od = __shfl_xor(bd, 32); int ok = __shfl_xor(bkm, 32);
        if (od < bd || (od == bd && ok < bkm)) { bd = od; bkm = ok; }
    }
    const int bk = multi ? bkm : kmin;

    if (hi == 0) bkArr[tokb] = bk;
    __syncthreads();

    // ---- epilogue: gather W rows (L2-hot), coalesced NCHW store ----
    {
        const int pp = tid & 255;            // token
        const int dh = tid >> 8;             // dim half 0..1
        const int kk = bkArr[pp];
        const float* wr = W + kk * 64 + dh * 32;
        float* ob = out + (size_t)b * 262144 + p0 + pp;
        #pragma unroll
        for (int j = 0; j < 8; ++j) {
            f32x4 v = *(const f32x4*)(wr + j * 4);
            ob[(size_t)(dh * 32 + j * 4 + 0) * HW_] = v[0];
            ob[(size_t)(dh * 32 + j * 4 + 1) * HW_] = v[1];
            ob[(size_t)(dh * 32 + j * 4 + 2) * HW_] = v[2];
            ob[(size_t)(dh * 32 + j * 4 + 3) * HW_] = v[3];
        }
    }
}

extern "C" void kernel_launch(void* const* d_in, const int* in_sizes, int n_in,
                              void* d_out, int out_size, void* d_ws, size_t ws_size,
                              hipStream_t stream) {
    const float* x = (const float*)d_in[0];
    const float* W = (const float*)d_in[1];
    unsigned short* Wb = (unsigned short*)d_ws;              // 64 KiB image
    float* nh = (float*)((char*)d_ws + 65536);               // 512 f32
    int* wmax2i = (int*)((char*)d_ws + 65536 + 2048);        // 1 int (float bits)
    hipMemsetAsync(wmax2i, 0, 4, stream);
    vq_prep<<<512, 64, 0, stream>>>(W, Wb, nh, wmax2i);
    vq_main<<<512, 512, 0, stream>>>(x, W, Wb, nh, wmax2i, (float*)d_out);
}